// Round 6
// baseline (119.815 us; speedup 1.0000x reference)
//
#include <hip/hip_runtime.h>
#include <hip/hip_bf16.h>

// dist[b,c] = ||x_b||^2 + ||p_c||^2 - 2 x_b . p_c
// B=16384, D=512, C=1000 (padded to 1024 in workspace)

#define B_ROWS 16384
#define D_K    512
#define C_COLS 1000
#define C_PAD  1024

#define BM 256
#define BN 128
#define BK 32
#define NK (D_K / BK)   // 16
#define NBUF 4          // 4-deep LDS pipeline, stage 3 K-tiles ahead
#define ABUF_SH 8192    // A ushorts per buffer (256 rows x 32 k)
#define BBUF_SH 4096    // B ushorts per buffer (128 rows x 32 k)
#define TILE_SH 12288   // ushorts per buffer (A + B) = 24 KiB

typedef __attribute__((ext_vector_type(8))) short short8;
typedef __attribute__((ext_vector_type(16))) float f32x16;

// fp32 -> bf16 round-to-nearest-even
__device__ __forceinline__ unsigned short f2bf(float f) {
  unsigned u = __float_as_uint(f);
  u += 0x7fffu + ((u >> 16) & 1u);
  return (unsigned short)(u >> 16);
}

// 16-byte async global->LDS copy (lane-contiguous LDS destination)
__device__ __forceinline__ void gload16(const void* g, void* l) {
  __builtin_amdgcn_global_load_lds(
      (const __attribute__((address_space(1))) unsigned int*)g,
      (__attribute__((address_space(3))) unsigned int*)l, 16, 0, 0);
}

// One wave per row: cast row to bf16 + fp32 sum of squares.
// Rows [0, B_ROWS) -> x;  rows [B_ROWS, B_ROWS + C_PAD) -> protomat (zero-padded past C_COLS).
__global__ __launch_bounds__(256) void prep_kernel(
    const float* __restrict__ x, const float* __restrict__ p,
    unsigned short* __restrict__ xb, unsigned short* __restrict__ pb,
    float* __restrict__ xsq, float* __restrict__ psq) {
  const int wave = threadIdx.x >> 6;
  const int lane = threadIdx.x & 63;
  const int row  = blockIdx.x * 4 + wave;
  const bool isx = row < B_ROWS;
  const int r2   = isx ? row : row - B_ROWS;

  float v[8];
  if (isx) {
    const float4* s = reinterpret_cast<const float4*>(x + (size_t)r2 * D_K + lane * 8);
    float4 a = s[0], b = s[1];
    v[0] = a.x; v[1] = a.y; v[2] = a.z; v[3] = a.w;
    v[4] = b.x; v[5] = b.y; v[6] = b.z; v[7] = b.w;
  } else if (r2 < C_COLS) {
    const float4* s = reinterpret_cast<const float4*>(p + (size_t)r2 * D_K + lane * 8);
    float4 a = s[0], b = s[1];
    v[0] = a.x; v[1] = a.y; v[2] = a.z; v[3] = a.w;
    v[4] = b.x; v[5] = b.y; v[6] = b.z; v[7] = b.w;
  } else {
#pragma unroll
    for (int j = 0; j < 8; ++j) v[j] = 0.0f;
  }

  float ss = 0.0f;
  unsigned short u[8];
#pragma unroll
  for (int j = 0; j < 8; ++j) { ss += v[j] * v[j]; u[j] = f2bf(v[j]); }

  uint4 pk;
  pk.x = (unsigned)u[0] | ((unsigned)u[1] << 16);
  pk.y = (unsigned)u[2] | ((unsigned)u[3] << 16);
  pk.z = (unsigned)u[4] | ((unsigned)u[5] << 16);
  pk.w = (unsigned)u[6] | ((unsigned)u[7] << 16);
  unsigned short* dst = (isx ? xb : pb) + (size_t)r2 * D_K + lane * 8;
  *reinterpret_cast<uint4*>(dst) = pk;

#pragma unroll
  for (int off = 32; off > 0; off >>= 1) ss += __shfl_down(ss, off);
  if (lane == 0) (isx ? xsq : psq)[r2] = ss;
}

// 256x128 tile, 2 passes per block (bn and bn+4: pass-0 stores drain to HBM
// under pass-1's K-loop). 8 waves (4M x 2N), per-wave 64x64 via 2x2 of
// mfma_f32_32x32x16_bf16. 4-deep LDS pipeline with counted vmcnt (stage 3
// ahead, never drain mid-loop), chunk-permuted conflict-free LDS, XCD
// swizzle, setprio around MFMA, fused distance epilogue.
//
// LDS chunk layout (per A/B region): fragment (row, kslot) [kslot = 8-elem
// k-group 0..3] at chunk row*4 + ((kslot + (row>>1)) & 3). Staging chunk ch
// loads global k-group ((ch&3) - ((ch>>2)>>1)) & 3. 32x32x16 fragment:
// row = lane&31, k = (lane>>5)*8 + e -> kslot = kg*2 + (lane>>5); read pos
// = ((lane>>5) + ((lane&31)>>1)) & 3; kg toggle = byte-addr XOR 32 (ushort
// index XOR 16). Verified: each 8-lane group covers all 8 16B-slots ->
// conflict-free ds_read_b128.
//
// Iteration t: vmcnt(6) -> s_barrier -> STAGE(t+3 -> buf[(t+3)&3]) ->
// COMPUTE(t). STAGE after the barrier: buf[(t-1)&3]'s readers passed it ->
// no WAR race. vmcnt(6) = tiles t+1,t+2 in flight (3 loads each); tile t
// guaranteed landed. Tail: 6/3/0. Cross-pass reuse safe: pass-0's tail
// barriers retire all readers of bufs 0..2 before pass-1 restages them.
__global__ __launch_bounds__(512, 2) void gemm_kernel(
    const unsigned short* __restrict__ xb, const unsigned short* __restrict__ pb,
    const float* __restrict__ xsq, const float* __restrict__ psq,
    float* __restrict__ out) {
  __shared__ __align__(16) unsigned short L[NBUF * TILE_SH];  // 96 KiB

  const int tid  = threadIdx.x;
  const int lane = tid & 63;
  const int wave = tid >> 6;
  const int wm   = wave >> 1;  // 0..3 (M)
  const int wn   = wave & 1;   // 0..1 (N)

  // XCD swizzle: 256 blocks; XCD x gets bm in [x*8, x*8+8), all 4 bn-pairs.
  const int bid = blockIdx.x;
  const int tt  = (bid & 7) * 32 + (bid >> 3);
  const int bm  = tt >> 2;  // 0..63
  const int bn  = tt & 3;   // 0..3 (pair base; passes use bn, bn+4)

  // Staging: A chunks tid, tid+512 (1024 chunks); B chunk tid (512 chunks).
  const int chA0 = tid, chA1 = tid + 512;
  const int rA0 = chA0 >> 2, rA1 = chA1 >> 2, rB = tid >> 2;
  const int ksA0 = ((chA0 & 3) - (rA0 >> 1)) & 3;
  const int ksA1 = ((chA1 & 3) - (rA1 >> 1)) & 3;
  const int ksB  = ((tid & 3) - (rB >> 1)) & 3;
  const unsigned short* gA0 = xb + ((size_t)bm * BM + rA0) * D_K + ksA0 * 8;
  const unsigned short* gA1 = xb + ((size_t)bm * BM + rA1) * D_K + ksA1 * 8;
  unsigned short* lA0 = &L[chA0 * 8];
  unsigned short* lA1 = &L[chA1 * 8];
  unsigned short* lB0 = &L[ABUF_SH + tid * 8];

  // ds_read bases (ushort units).
  const int row_l = lane & 31;
  const int pos   = (((lane >> 5) + (row_l >> 1)) & 3);
  const int rdA0  = (wm * 64 + row_l) * 32 + pos * 8;
  const int rdA1  = rdA0 ^ 16;  // kg=1 (pos XOR 2)
  const int rdB0  = (wn * 64 + row_l) * 32 + pos * 8;
  const int rdB1  = rdB0 ^ 16;

  f32x16 acc0, acc1, acc2, acc3;
  const unsigned short* gBp = nullptr;  // set per pass

  auto STAGE = [&](int T, int BUF) {
    const int ko = T * BK;
    const int bo = BUF * TILE_SH;
    gload16(gA0 + ko, lA0 + bo);
    gload16(gA1 + ko, lA1 + bo);
    gload16(gBp + ko, lB0 + bo);
  };

  auto COMPUTE = [&](int BUF) {
    const unsigned short* Ab = &L[BUF * TILE_SH];
    const unsigned short* Bb = Ab + ABUF_SH;
    short8 a00 = *reinterpret_cast<const short8*>(Ab + rdA0);
    short8 a01 = *reinterpret_cast<const short8*>(Ab + rdA1);
    short8 a10 = *reinterpret_cast<const short8*>(Ab + rdA0 + 1024);
    short8 a11 = *reinterpret_cast<const short8*>(Ab + rdA1 + 1024);
    short8 b00 = *reinterpret_cast<const short8*>(Bb + rdB0);
    short8 b01 = *reinterpret_cast<const short8*>(Bb + rdB1);
    short8 b10 = *reinterpret_cast<const short8*>(Bb + rdB0 + 1024);
    short8 b11 = *reinterpret_cast<const short8*>(Bb + rdB1 + 1024);
    __builtin_amdgcn_s_setprio(1);
    acc0 = __builtin_amdgcn_mfma_f32_32x32x16_bf16(a00, b00, acc0, 0, 0, 0);
    acc0 = __builtin_amdgcn_mfma_f32_32x32x16_bf16(a01, b01, acc0, 0, 0, 0);
    acc1 = __builtin_amdgcn_mfma_f32_32x32x16_bf16(a00, b10, acc1, 0, 0, 0);
    acc1 = __builtin_amdgcn_mfma_f32_32x32x16_bf16(a01, b11, acc1, 0, 0, 0);
    acc2 = __builtin_amdgcn_mfma_f32_32x32x16_bf16(a10, b00, acc2, 0, 0, 0);
    acc2 = __builtin_amdgcn_mfma_f32_32x32x16_bf16(a11, b01, acc2, 0, 0, 0);
    acc3 = __builtin_amdgcn_mfma_f32_32x32x16_bf16(a10, b10, acc3, 0, 0, 0);
    acc3 = __builtin_amdgcn_mfma_f32_32x32x16_bf16(a11, b11, acc3, 0, 0, 0);
    __builtin_amdgcn_s_setprio(0);
  };

#pragma unroll 1
  for (int pass = 0; pass < 2; ++pass) {
    const int bn2 = bn + 4 * pass;
    gBp = pb + ((size_t)bn2 * BN + rB) * D_K + ksB * 8;

    const f32x16 z = {0.f};
    acc0 = z; acc1 = z; acc2 = z; acc3 = z;

    STAGE(0, 0);
    STAGE(1, 1);
    STAGE(2, 2);

#pragma unroll 1
    for (int t = 0; t < NK - 3; ++t) {  // t = 0..12
      asm volatile("s_waitcnt vmcnt(6)" ::: "memory");  // tile t landed
      __builtin_amdgcn_s_barrier();
      STAGE(t + 3, (t + 3) & 3);
      COMPUTE(t & 3);
    }
    asm volatile("s_waitcnt vmcnt(6)" ::: "memory");  // tile 13 landed
    __builtin_amdgcn_s_barrier();
    COMPUTE(1);
    asm volatile("s_waitcnt vmcnt(3)" ::: "memory");  // tile 14 landed
    __builtin_amdgcn_s_barrier();
    COMPUTE(2);
    asm volatile("s_waitcnt vmcnt(0)" ::: "memory");
    __builtin_amdgcn_s_barrier();
    COMPUTE(3);

    // Epilogue: out[b][c] = xsq[b] + psq[c] - 2*cross. 32 contiguous lanes
    // per store group = 128B coalescing. Stores drain under next pass.
    const int colb = bn2 * BN + wn * 64 + row_l;
    const float pc0 = psq[colb];
    const float pc1 = psq[colb + 32];
    const int rowb = bm * BM + wm * 64 + ((lane >> 5) << 2);

#define EPI(ACCL, ACCR, MM)                                                  \
    _Pragma("unroll") for (int g = 0; g < 4; ++g) {                          \
      _Pragma("unroll") for (int r = 0; r < 4; ++r) {                        \
        const int reg = g * 4 + r;                                           \
        const int row = rowb + (MM)*32 + g * 8 + r;                          \
        const float xs = xsq[row];                                           \
        if (colb < C_COLS)                                                   \
          out[(size_t)row * C_COLS + colb] = xs + pc0 - 2.0f * ACCL[reg];    \
        if (colb + 32 < C_COLS)                                              \
          out[(size_t)row * C_COLS + colb + 32] = xs + pc1 - 2.0f * ACCR[reg];\
      }                                                                      \
    }
    EPI(acc0, acc1, 0)
    EPI(acc2, acc3, 1)
#undef EPI
  }
}

extern "C" void kernel_launch(void* const* d_in, const int* in_sizes, int n_in,
                              void* d_out, int out_size, void* d_ws, size_t ws_size,
                              hipStream_t stream) {
  const float* x = (const float*)d_in[0];
  const float* p = (const float*)d_in[1];
  float* out = (float*)d_out;

  char* ws = (char*)d_ws;
  unsigned short* xb  = (unsigned short*)ws;                        // 16384*512*2 = 16 MiB
  unsigned short* pb  = (unsigned short*)(ws + 16777216);           // 1024*512*2  = 1 MiB
  float* xsq          = (float*)(ws + 16777216 + 1048576);          // 64 KiB
  float* psq          = (float*)(ws + 16777216 + 1048576 + 65536);  // 4 KiB

  // Prep: one wave per row, (16384 + 1024) rows / 4 waves per block
  prep_kernel<<<(B_ROWS + C_PAD) / 4, 256, 0, stream>>>(x, p, xb, pb, xsq, psq);

  // GEMM: 256 blocks (64 bm x 4 bn-pairs), XCD-swizzled, 512 threads,
  // 2 output tiles per block (bn, bn+4)
  gemm_kernel<<<256, 512, 0, stream>>>(xb, pb, xsq, psq, out);
}

// Round 7
// 114.823 us; speedup vs baseline: 1.0435x; 1.0435x over previous
//
#include <hip/hip_runtime.h>
#include <hip/hip_bf16.h>

// dist[b,c] = ||x_b||^2 + ||p_c||^2 - 2 x_b . p_c
// B=16384, D=512, C=1000 (padded to 1024 in workspace)

#define B_ROWS 16384
#define D_K    512
#define C_COLS 1000
#define C_PAD  1024

#define BM 256
#define BN 256
#define BK 64
#define NT (D_K / BK)  // 8 K-tiles

typedef __attribute__((ext_vector_type(8))) short short8;
typedef __attribute__((ext_vector_type(4))) float f32x4;

// fp32 -> bf16 round-to-nearest-even
__device__ __forceinline__ unsigned short f2bf(float f) {
  unsigned u = __float_as_uint(f);
  u += 0x7fffu + ((u >> 16) & 1u);
  return (unsigned short)(u >> 16);
}

__device__ __forceinline__ void gload16(const void* g, void* l) {
  __builtin_amdgcn_global_load_lds(
      (const __attribute__((address_space(1))) unsigned int*)g,
      (__attribute__((address_space(3))) unsigned int*)l, 16, 0, 0);
}

__device__ __forceinline__ f32x4 MFMA(short8 a, short8 b, f32x4 c) {
  return __builtin_amdgcn_mfma_f32_16x16x32_bf16(a, b, c, 0, 0, 0);
}

// One wave per row: cast row to bf16 + fp32 sum of squares.
__global__ __launch_bounds__(256) void prep_kernel(
    const float* __restrict__ x, const float* __restrict__ p,
    unsigned short* __restrict__ xb, unsigned short* __restrict__ pb,
    float* __restrict__ xsq, float* __restrict__ psq) {
  const int wave = threadIdx.x >> 6;
  const int lane = threadIdx.x & 63;
  const int row  = blockIdx.x * 4 + wave;
  const bool isx = row < B_ROWS;
  const int r2   = isx ? row : row - B_ROWS;

  float v[8];
  if (isx) {
    const float4* s = reinterpret_cast<const float4*>(x + (size_t)r2 * D_K + lane * 8);
    float4 a = s[0], b = s[1];
    v[0] = a.x; v[1] = a.y; v[2] = a.z; v[3] = a.w;
    v[4] = b.x; v[5] = b.y; v[6] = b.z; v[7] = b.w;
  } else if (r2 < C_COLS) {
    const float4* s = reinterpret_cast<const float4*>(p + (size_t)r2 * D_K + lane * 8);
    float4 a = s[0], b = s[1];
    v[0] = a.x; v[1] = a.y; v[2] = a.z; v[3] = a.w;
    v[4] = b.x; v[5] = b.y; v[6] = b.z; v[7] = b.w;
  } else {
#pragma unroll
    for (int j = 0; j < 8; ++j) v[j] = 0.0f;
  }

  float ss = 0.0f;
  unsigned short u[8];
#pragma unroll
  for (int j = 0; j < 8; ++j) { ss += v[j] * v[j]; u[j] = f2bf(v[j]); }

  uint4 pk;
  pk.x = (unsigned)u[0] | ((unsigned)u[1] << 16);
  pk.y = (unsigned)u[2] | ((unsigned)u[3] << 16);
  pk.z = (unsigned)u[4] | ((unsigned)u[5] << 16);
  pk.w = (unsigned)u[6] | ((unsigned)u[7] << 16);
  unsigned short* dst = (isx ? xb : pb) + (size_t)r2 * D_K + lane * 8;
  *reinterpret_cast<uint4*>(dst) = pk;

#pragma unroll
  for (int off = 32; off > 0; off >>= 1) ss += __shfl_down(ss, off);
  if (lane == 0) (isx ? xsq : psq)[r2] = ss;
}

// 256x256 tile, BK=64, 8 waves (2M x 4N, 128x64/wave), 16x16x32 MFMA,
// acc[8][4]. 8-phase-style schedule: each K-tile = 4 phases, each phase
// {stage one 16KiB group; [vmcnt]; BAR1; ds_read subtile; setprio(1);
// 16 MFMA; setprio(0); lgkmcnt(0); BAR2}. Counted vmcnt(8) twice per
// tile (tail 8/8/4/0) keeps 4-5 stage-groups in flight across barriers.
//
// LDS: 2 bufs x {A-k0, A-k1, B-k0, B-k1} regions of 8192 ush (256 rows x
// 32 k) = 128 KiB. Region chunk layout: frag (row, kslot) at chunk
// row*4 + ((kslot + (row>>1)) & 3) (round-5-verified conflict-free for the
// 16x16x32 read pattern). Stage group (tile T, half h, A|B): 2 gload16 per
// thread (rows tid>>2 and +128, kslot ((tid&3)-(tid>>3... see ks_s)).
//
// Stage schedule (group = {A,B} x {k0,k1} of a tile):
//   prologue: A(0,0) B(0,0) A(0,1) B(0,1) A(1,0) B(1,0)
//   tile T:  p0 stages A(T+1,1), p1 B(T+1,1), p2 A(T+2,0), p3 B(T+2,0)
// WAR: a stage at phase p overwrites a region last ds_read at phase p-1;
// p-1's reads are drained (lgkmcnt(0)) before BAR2(p-1), and the stage sits
// after that barrier -> safe. vmcnt ledger (in-order retirement, 2 loads per
// group) verified: steady p0/p2 need <=8 outstanding to guarantee the
// consumed groups landed; tail needs 8/8 (T=6), 4/0 (T=7).
__global__ __launch_bounds__(512, 2) void gemm_kernel(
    const unsigned short* __restrict__ xb, const unsigned short* __restrict__ pb,
    const float* __restrict__ xsq, const float* __restrict__ psq,
    float* __restrict__ out) {
  __shared__ __align__(16) unsigned short L[65536];  // 128 KiB
  unsigned short* Lp = L;

  const int tid  = threadIdx.x;
  const int lane = tid & 63;
  const int wave = tid >> 6;
  const int wm   = wave >> 2;  // 0..1 (M half)
  const int wn   = wave & 3;   // 0..3 (N quarter)

  // XCD swizzle: XCD x gets bm in [x*8, x*8+8), all 4 bn.
  const int bid = blockIdx.x;
  const int tt  = (bid & 7) * 32 + (bid >> 3);
  const int bm  = tt >> 2;  // 0..63
  const int bn  = tt & 3;   // 0..3

  // Staging: per thread, rows r_s and r_s+128 of the group, kslot ks_s.
  const int r_s  = tid >> 2;
  const int ks_s = ((tid & 3) - (r_s >> 1)) & 3;
  const unsigned short* gA = xb + ((size_t)bm * BM + r_s) * D_K + ks_s * 8;
  const unsigned short* gB = pb + ((size_t)bn * BN + r_s) * D_K + ks_s * 8;

#define STAGE_A(T, H)                                                        \
  do {                                                                       \
    const int off_ = (T) * 64 + (H) * 32;                                    \
    unsigned short* d_ = Lp + (((T) & 1) * 32768 + (H) * 8192 + tid * 8);    \
    gload16(gA + off_, d_);                                                  \
    gload16(gA + off_ + 65536, d_ + 4096);                                   \
  } while (0)

#define STAGE_B(T, H)                                                        \
  do {                                                                       \
    const int off_ = (T) * 64 + (H) * 32;                                    \
    unsigned short* d_ =                                                     \
        Lp + (((T) & 1) * 32768 + 16384 + (H) * 8192 + tid * 8);             \
    gload16(gB + off_, d_);                                                  \
    gload16(gB + off_ + 65536, d_ + 4096);                                   \
  } while (0)

  f32x4 acc[8][4];
#pragma unroll
  for (int m = 0; m < 8; ++m)
#pragma unroll
    for (int n = 0; n < 4; ++n) acc[m][n] = (f32x4){0.f, 0.f, 0.f, 0.f};

  // ds_read bases (ushort units) within a region.
  const int l15  = lane & 15;
  const int posL = (((lane >> 4) + (l15 >> 1)) & 3);
  const int rdA  = (wm * 128 + l15) * 32 + posL * 8;
  const int rdB  = 16384 + (wn * 64 + l15) * 32 + posL * 8;

  short8 bF0, bF1, bF2, bF3;

#define VM8  asm volatile("s_waitcnt vmcnt(8)" ::: "memory")
#define VM4  asm volatile("s_waitcnt vmcnt(4)" ::: "memory")
#define VM0  asm volatile("s_waitcnt vmcnt(0)" ::: "memory")
#define NOVM (void)0

#define PH(BUF, H, MH, STAGE_STMT, VM_STMT)                                   \
  do {                                                                        \
    STAGE_STMT;                                                               \
    VM_STMT;                                                                  \
    asm volatile("" ::: "memory");                                            \
    __builtin_amdgcn_s_barrier();                                             \
    const unsigned short* Ap_ =                                               \
        Lp + (BUF) * 32768 + (H) * 8192 + rdA + (MH) * 2048;                  \
    short8 aF0 = *reinterpret_cast<const short8*>(Ap_ + 0);                   \
    short8 aF1 = *reinterpret_cast<const short8*>(Ap_ + 512);                 \
    short8 aF2 = *reinterpret_cast<const short8*>(Ap_ + 1024);                \
    short8 aF3 = *reinterpret_cast<const short8*>(Ap_ + 1536);                \
    if ((MH) == 0) {                                                          \
      const unsigned short* Bp_ = Lp + (BUF) * 32768 + (H) * 8192 + rdB;      \
      bF0 = *reinterpret_cast<const short8*>(Bp_ + 0);                        \
      bF1 = *reinterpret_cast<const short8*>(Bp_ + 512);                      \
      bF2 = *reinterpret_cast<const short8*>(Bp_ + 1024);                     \
      bF3 = *reinterpret_cast<const short8*>(Bp_ + 1536);                     \
    }                                                                         \
    __builtin_amdgcn_s_setprio(1);                                            \
    acc[(MH)*4+0][0] = MFMA(aF0, bF0, acc[(MH)*4+0][0]);                      \
    acc[(MH)*4+0][1] = MFMA(aF0, bF1, acc[(MH)*4+0][1]);                      \
    acc[(MH)*4+0][2] = MFMA(aF0, bF2, acc[(MH)*4+0][2]);                      \
    acc[(MH)*4+0][3] = MFMA(aF0, bF3, acc[(MH)*4+0][3]);                      \
    acc[(MH)*4+1][0] = MFMA(aF1, bF0, acc[(MH)*4+1][0]);                      \
    acc[(MH)*4+1][1] = MFMA(aF1, bF1, acc[(MH)*4+1][1]);                      \
    acc[(MH)*4+1][2] = MFMA(aF1, bF2, acc[(MH)*4+1][2]);                      \
    acc[(MH)*4+1][3] = MFMA(aF1, bF3, acc[(MH)*4+1][3]);                      \
    acc[(MH)*4+2][0] = MFMA(aF2, bF0, acc[(MH)*4+2][0]);                      \
    acc[(MH)*4+2][1] = MFMA(aF2, bF1, acc[(MH)*4+2][1]);                      \
    acc[(MH)*4+2][2] = MFMA(aF2, bF2, acc[(MH)*4+2][2]);                      \
    acc[(MH)*4+2][3] = MFMA(aF2, bF3, acc[(MH)*4+2][3]);                      \
    acc[(MH)*4+3][0] = MFMA(aF3, bF0, acc[(MH)*4+3][0]);                      \
    acc[(MH)*4+3][1] = MFMA(aF3, bF1, acc[(MH)*4+3][1]);                      \
    acc[(MH)*4+3][2] = MFMA(aF3, bF2, acc[(MH)*4+3][2]);                      \
    acc[(MH)*4+3][3] = MFMA(aF3, bF3, acc[(MH)*4+3][3]);                      \
    __builtin_amdgcn_s_setprio(0);                                            \
    asm volatile("s_waitcnt lgkmcnt(0)" ::: "memory");                        \
    __builtin_amdgcn_s_barrier();                                             \
  } while (0)

  // Prologue: 6 stage groups (12 loads).
  STAGE_A(0, 0); STAGE_B(0, 0);
  STAGE_A(0, 1); STAGE_B(0, 1);
  STAGE_A(1, 0); STAGE_B(1, 0);

#pragma unroll 1
  for (int T = 0; T < 6; ++T) {
    const int c = T & 1;
    PH(c, 0, 0, STAGE_A(T + 1, 1), VM8);
    PH(c, 0, 1, STAGE_B(T + 1, 1), NOVM);
    PH(c, 1, 0, STAGE_A(T + 2, 0), VM8);
    PH(c, 1, 1, STAGE_B(T + 2, 0), NOVM);
  }
  // T = 6 (buf 0): only k1-stages of tile 7 remain.
  PH(0, 0, 0, STAGE_A(7, 1), VM8);
  PH(0, 0, 1, STAGE_B(7, 1), NOVM);
  PH(0, 1, 0, NOVM, VM8);
  PH(0, 1, 1, NOVM, NOVM);
  // T = 7 (buf 1): no stages; drain 4 then 0.
  PH(1, 0, 0, NOVM, VM4);
  PH(1, 0, 1, NOVM, NOVM);
  PH(1, 1, 0, NOVM, VM0);
  PH(1, 1, 1, NOVM, NOVM);

#undef PH
#undef STAGE_A
#undef STAGE_B

  // Epilogue: out[b][c] = xsq[b] + psq[c] - 2*cross
  const int colb = bn * BN + wn * 64 + l15;
  float pc[4];
#pragma unroll
  for (int n = 0; n < 4; ++n) pc[n] = psq[colb + n * 16];  // C_PAD-sized: in bounds

  const int rowb = bm * BM + wm * 128 + ((lane >> 4) << 2);
#pragma unroll
  for (int m = 0; m < 8; ++m) {
#pragma unroll
    for (int r = 0; r < 4; ++r) {
      const int row = rowb + m * 16 + r;
      const float xs = xsq[row];
#pragma unroll
      for (int n = 0; n < 4; ++n) {
        const int c = colb + n * 16;
        if (c < C_COLS)
          out[(size_t)row * C_COLS + c] = xs + pc[n] - 2.0f * acc[m][n][r];
      }
    }
  }
}

extern "C" void kernel_launch(void* const* d_in, const int* in_sizes, int n_in,
                              void* d_out, int out_size, void* d_ws, size_t ws_size,
                              hipStream_t stream) {
  const float* x = (const float*)d_in[0];
  const float* p = (const float*)d_in[1];
  float* out = (float*)d_out;

  char* ws = (char*)d_ws;
  unsigned short* xb  = (unsigned short*)ws;                        // 16 MiB
  unsigned short* pb  = (unsigned short*)(ws + 16777216);           // 1 MiB
  float* xsq          = (float*)(ws + 16777216 + 1048576);          // 64 KiB
  float* psq          = (float*)(ws + 16777216 + 1048576 + 65536);  // 4 KiB

  prep_kernel<<<(B_ROWS + C_PAD) / 4, 256, 0, stream>>>(x, p, xb, pb, xsq, psq);

  // GEMM: 256 blocks (64 bm x 4 bn), XCD-swizzled, 512 threads
  gemm_kernel<<<256, 512, 0, stream>>>(xb, pb, xsq, psq, out);
}